// Round 2
// baseline (2508.320 us; speedup 1.0000x reference)
//
#include <hip/hip_runtime.h>
#include <hip/hip_bf16.h>

// B=64 (LSTM time axis via torch batch_first quirk), L=64 (only col 63 used),
// N=256, C=8, Ct=4 -> NQ=1024 sequences, H=128, 4H=512, RH1=128, RH2=64, S=4.

__device__ __forceinline__ float sigf(float x)   { return 1.0f / (1.0f + __expf(-x)); }
__device__ __forceinline__ float tanh_f(float x) { return 1.0f - 2.0f / (__expf(2.0f * x) + 1.0f); }

// ---------------- init: cur <- x[:, 63, :, :] ----------------
__global__ void init_cur_k(const float* __restrict__ x, float* __restrict__ cur)
{
    int i   = blockIdx.x * 256 + threadIdx.x;   // 0 .. 524287
    int b   = i >> 13;
    int rem = i & 8191;
    cur[i] = x[(size_t)b * 524288 + 63 * 8192 + rem];
}

// ---------------- weight transposes (k-major), once per launch ----------------
__global__ void transpose_w_k(const float* __restrict__ W1, const float* __restrict__ W2,
                              const float* __restrict__ W3, float* __restrict__ w1t,
                              float* __restrict__ w2t, float* __restrict__ w3t)
{
    int i = blockIdx.x * 256 + threadIdx.x;
    if (i < 257 * 128) {                                    // w1t[k][o], k<257, o<128
        int k = i >> 7, o = i & 127;
        w1t[i] = W1[o * 257 + k];
    } else if (i < 257 * 128 + 128 * 64) {                  // w2t[k][o], k<128, o<64
        int j = i - 257 * 128;
        int k = j >> 6, o = j & 63;
        w2t[j] = W2[o * 128 + k];
    } else if (i < 257 * 128 + 128 * 64 + 64 * 8) {         // w3t[k][o], k<64, o<8
        int j = i - 257 * 128 - 128 * 64;
        int k = j >> 3, o = j & 7;
        w3t[j] = W3[o * 64 + k];
    }
}

// ---------------- LSTM scan for one roll (K-split, 16 waves/CU) ----------------
// 256 wgs x 1024 thr. wg owns sequences q0..q0+3. Thread (g=t>>1, half=t&1)
// holds W_hh[g][half*64..+63] in 64 VGPRs; partials combined via shfl_xor lane^1.
__global__ __launch_bounds__(1024, 4) void lstm_roll_k(
    const float* __restrict__ cur, const float* __restrict__ W_ih,
    const float* __restrict__ W_hh, const float* __restrict__ b_ih,
    const float* __restrict__ b_hh, float* __restrict__ hs)
{
    __shared__ __align__(16) float hL[4][128];
    __shared__ float pre[4][512];

    const int t    = threadIdx.x;
    const int g    = t >> 1, half = t & 1;
    const int q0   = blockIdx.x * 4;

    float w[64];
#pragma unroll
    for (int k = 0; k < 64; ++k) w[k] = W_hh[g * 128 + half * 64 + k];
    float wih[4];
#pragma unroll
    for (int c = 0; c < 4; ++c) wih[c] = W_ih[g * 8 + half * 4 + c];
    const float bsum = half ? 0.0f : (b_ih[g] + b_hh[g]);

    if (t < 512) ((float*)hL)[t] = 0.0f;
    float cc = 0.0f;
    const int s2 = t >> 7, j2 = t & 127;          // phase-2 job (valid for t<512)
    __syncthreads();

    for (int step = 0; step < 64; ++step) {
        // ---- phase 1: partial preact over this thread's K-half ----
        const float* __restrict__ xr = cur + step * 8192 + q0 * 8 + half * 4;
        float a0 = bsum, a1 = bsum, a2 = bsum, a3 = bsum;
        {
            float4 x0 = *(const float4*)(xr);
            float4 x1 = *(const float4*)(xr + 8);
            float4 x2 = *(const float4*)(xr + 16);
            float4 x3 = *(const float4*)(xr + 24);
            a0 += x0.x * wih[0] + x0.y * wih[1] + x0.z * wih[2] + x0.w * wih[3];
            a1 += x1.x * wih[0] + x1.y * wih[1] + x1.z * wih[2] + x1.w * wih[3];
            a2 += x2.x * wih[0] + x2.y * wih[1] + x2.z * wih[2] + x2.w * wih[3];
            a3 += x3.x * wih[0] + x3.y * wih[1] + x3.z * wih[2] + x3.w * wih[3];
        }
#pragma unroll
        for (int jq = 0; jq < 16; ++jq) {
            float4 h0 = *(const float4*)&hL[0][half * 64 + jq * 4];
            float4 h1 = *(const float4*)&hL[1][half * 64 + jq * 4];
            float4 h2 = *(const float4*)&hL[2][half * 64 + jq * 4];
            float4 h3 = *(const float4*)&hL[3][half * 64 + jq * 4];
            float w0 = w[jq * 4 + 0], w1 = w[jq * 4 + 1];
            float w2 = w[jq * 4 + 2], w3 = w[jq * 4 + 3];
            a0 += h0.x * w0 + h0.y * w1 + h0.z * w2 + h0.w * w3;
            a1 += h1.x * w0 + h1.y * w1 + h1.z * w2 + h1.w * w3;
            a2 += h2.x * w0 + h2.y * w1 + h2.z * w2 + h2.w * w3;
            a3 += h3.x * w0 + h3.y * w1 + h3.z * w2 + h3.w * w3;
        }
        a0 += __shfl_xor(a0, 1);
        a1 += __shfl_xor(a1, 1);
        a2 += __shfl_xor(a2, 1);
        a3 += __shfl_xor(a3, 1);
        if (!half) { pre[0][g] = a0; pre[1][g] = a1; pre[2][g] = a2; pre[3][g] = a3; }
        __syncthreads();

        // ---- phase 2: gates (torch order i,f,g,o) ----
        if (t < 512) {
            float pi = pre[s2][j2],       pf = pre[s2][128 + j2];
            float pg = pre[s2][256 + j2], po = pre[s2][384 + j2];
            cc = sigf(pf) * cc + sigf(pi) * tanh_f(pg);
            float hv = sigf(po) * tanh_f(cc);
            hL[s2][j2] = hv;
            hs[(size_t)(step * 1024 + q0 + s2) * 128 + j2] = hv;
        }
        __syncthreads();
    }
}

// ---------------- MLP + head for one roll ----------------
// 1024 wgs x 256 thr, 64 items/wg. thread (il=t&63, og=t>>6): 1 item x 32 outs (L1).
// Weights k-major from global (L1/L2 broadcast); activations k-major in LDS.
__global__ __launch_bounds__(256, 2) void mlp_roll_k(
    const float* __restrict__ hs, const float* __restrict__ hi,
    const float* __restrict__ r, int jstep,
    const float* __restrict__ w1t, const float* __restrict__ b1,
    const float* __restrict__ w2t, const float* __restrict__ b2,
    const float* __restrict__ w3t, const float* __restrict__ b3,
    const float* __restrict__ Wf, const float* __restrict__ bfp,
    float* __restrict__ cur, float* __restrict__ out)
{
    __shared__ __align__(16) float poolA[128 * 65];  // zT, then h2T (rows 0..63) + fsum (row 64)
    __shared__ __align__(16) float poolB[128 * 65];  // h1T, then prs (rows 0..7)

    const int t     = threadIdx.x;
    const int il    = t & 63, og = t >> 6;
    const int b     = blockIdx.x >> 4;
    const int qbase = (blockIdx.x & 15) * 64;
    const int q     = qbase + il, n = q >> 2;

    // ---- stage zT[k][item] = hs[b, qbase+item, k] ----
#pragma unroll
    for (int m = 0; m < 8; ++m) {
        int f = t + 256 * m;                  // 2048 float4s
        int item = f >> 5, kq = f & 31;
        float4 v = *(const float4*)&hs[(size_t)(b * 1024 + qbase + item) * 128 + kq * 4];
        poolA[(kq * 4 + 0) * 65 + item] = v.x;
        poolA[(kq * 4 + 1) * 65 + item] = v.y;
        poolA[(kq * 4 + 2) * 65 + item] = v.z;
        poolA[(kq * 4 + 3) * 65 + item] = v.w;
    }
    const float rb = r[b * 4 + jstep];
    __syncthreads();

    // ---- L1: acc[32] for outputs og*32+j over K=257 ----
    float acc[32];
    {
        const float4* b1v = (const float4*)(b1 + og * 32);
        const float4* rv4 = (const float4*)(w1t + 256 * 128 + og * 32);
#pragma unroll
        for (int jq = 0; jq < 8; ++jq) {
            float4 bv = b1v[jq], rv = rv4[jq];
            acc[jq * 4 + 0] = bv.x + rb * rv.x;
            acc[jq * 4 + 1] = bv.y + rb * rv.y;
            acc[jq * 4 + 2] = bv.z + rb * rv.z;
            acc[jq * 4 + 3] = bv.w + rb * rv.w;
        }
    }
#pragma unroll 2
    for (int k = 0; k < 128; ++k) {           // hs part
        float zv = poolA[k * 65 + il];
        const float* wr = w1t + k * 128 + og * 32;
#pragma unroll
        for (int jq = 0; jq < 8; ++jq) {
            float4 wv = *(const float4*)(wr + jq * 4);
            acc[jq * 4 + 0] += zv * wv.x; acc[jq * 4 + 1] += zv * wv.y;
            acc[jq * 4 + 2] += zv * wv.z; acc[jq * 4 + 3] += zv * wv.w;
        }
    }
    const float* __restrict__ hirow = hi + (size_t)(b * 256 + n) * 128;
#pragma unroll 2
    for (int k = 0; k < 128; ++k) {           // hi part
        float zv = hirow[k];
        const float* wr = w1t + (128 + k) * 128 + og * 32;
#pragma unroll
        for (int jq = 0; jq < 8; ++jq) {
            float4 wv = *(const float4*)(wr + jq * 4);
            acc[jq * 4 + 0] += zv * wv.x; acc[jq * 4 + 1] += zv * wv.y;
            acc[jq * 4 + 2] += zv * wv.z; acc[jq * 4 + 3] += zv * wv.w;
        }
    }
#pragma unroll
    for (int j = 0; j < 32; ++j)
        poolB[(og * 32 + j) * 65 + il] = fmaxf(acc[j], 0.0f);   // h1T
    __syncthreads();   // all zT reads done; h1T complete

    // ---- L2: acc2[16] for outputs og*16+j over K=128 ----
    float acc2[16];
    {
        const float4* b2v = (const float4*)(b2 + og * 16);
#pragma unroll
        for (int jq = 0; jq < 4; ++jq) {
            float4 bv = b2v[jq];
            acc2[jq * 4 + 0] = bv.x; acc2[jq * 4 + 1] = bv.y;
            acc2[jq * 4 + 2] = bv.z; acc2[jq * 4 + 3] = bv.w;
        }
    }
#pragma unroll 2
    for (int k = 0; k < 128; ++k) {
        float zv = poolB[k * 65 + il];
        const float* wr = w2t + k * 64 + og * 16;
#pragma unroll
        for (int jq = 0; jq < 4; ++jq) {
            float4 wv = *(const float4*)(wr + jq * 4);
            acc2[jq * 4 + 0] += zv * wv.x; acc2[jq * 4 + 1] += zv * wv.y;
            acc2[jq * 4 + 2] += zv * wv.z; acc2[jq * 4 + 3] += zv * wv.w;
        }
    }
#pragma unroll
    for (int j = 0; j < 16; ++j)
        poolA[(og * 16 + j) * 65 + il] = fmaxf(acc2[j], 0.0f);  // h2T (zT dead)
    __syncthreads();

    // ---- L3: c = og*2, og*2+1 over K=64; write cur + prs ----
    float p0 = b3[og * 2], p1 = b3[og * 2 + 1];
#pragma unroll 4
    for (int k = 0; k < 64; ++k) {
        float zv = poolA[k * 65 + il];
        p0 += zv * w3t[k * 8 + og * 2];
        p1 += zv * w3t[k * 8 + og * 2 + 1];
    }
    cur[(size_t)(b * 1024 + q) * 8 + og * 2]     = p0;
    cur[(size_t)(b * 1024 + q) * 8 + og * 2 + 1] = p1;
    poolB[(og * 2) * 65 + il]     = fmaxf(p0, 0.0f) * Wf[og * 2];      // prs (h1T dead)
    poolB[(og * 2 + 1) * 65 + il] = fmaxf(p1, 0.0f) * Wf[og * 2 + 1];
    __syncthreads();

    // ---- head: f per item, then sum 4 ct per n (includes Ct*bf as reference) ----
    if (t < 64) {
        float f = bfp[0];
#pragma unroll
        for (int c = 0; c < 8; ++c) f += poolB[c * 65 + t];
        poolA[64 * 65 + t] = f;
    }
    __syncthreads();
    if (t < 16) {
        const float* fs = &poolA[64 * 65];
        float v = fs[t * 4] + fs[t * 4 + 1] + fs[t * 4 + 2] + fs[t * 4 + 3];
        out[(size_t)(b * 256 + (qbase >> 2) + t) * 4 + jstep] = v;
    }
}

extern "C" void kernel_launch(void* const* d_in, const int* in_sizes, int n_in,
                              void* d_out, int out_size, void* d_ws, size_t ws_size,
                              hipStream_t stream)
{
    const float* x   = (const float*)d_in[0];
    const float* hi  = (const float*)d_in[1];
    const float* r   = (const float*)d_in[2];
    const float* Wih = (const float*)d_in[3];
    const float* Whh = (const float*)d_in[4];
    const float* bih = (const float*)d_in[5];
    const float* bhh = (const float*)d_in[6];
    const float* W1  = (const float*)d_in[7];
    const float* b1  = (const float*)d_in[8];
    const float* W2  = (const float*)d_in[9];
    const float* b2  = (const float*)d_in[10];
    const float* W3  = (const float*)d_in[11];
    const float* b3  = (const float*)d_in[12];
    const float* Wf  = (const float*)d_in[13];
    const float* bf  = (const float*)d_in[14];
    float* out = (float*)d_out;

    float* cur = (float*)d_ws;            // 524288 f
    float* hs  = cur + 524288;            // 8388608 f
    float* w1t = hs + 8388608;            // 32896 f
    float* w2t = w1t + 32896;             // 8192 f
    float* w3t = w2t + 8192;              // 512 f

    init_cur_k<<<2048, 256, 0, stream>>>(x, cur);
    transpose_w_k<<<163, 256, 0, stream>>>(W1, W2, W3, w1t, w2t, w3t);
    for (int j = 0; j < 4; ++j) {
        lstm_roll_k<<<256, 1024, 0, stream>>>(cur, Wih, Whh, bih, bhh, hs);
        mlp_roll_k<<<1024, 256, 0, stream>>>(hs, hi, r, j, w1t, b1, w2t, b2,
                                             w3t, b3, Wf, bf, cur, out);
    }
}

// Round 3
// 1009.601 us; speedup vs baseline: 2.4845x; 2.4845x over previous
//
#include <hip/hip_runtime.h>
#include <hip/hip_bf16.h>

// B=64 (LSTM time axis via torch batch_first quirk), L=64 (only col 63 used),
// N=256, C=8, Ct=4 -> NQ=1024 sequences, H=128, 4H=512, RH1=128, RH2=64, S=4.
//
// MLP path uses split-bf16 MFMA: f = hi + lo (two bf16), products via 3 MFMAs
// (hi*hi + hi*lo + lo*hi) accumulating fp32 -> ~2^-17 relative error, fp32-like.

typedef __attribute__((ext_vector_type(8))) short short8;   // 8 bf16 in 4 VGPRs
typedef __attribute__((ext_vector_type(4))) float f32x4;

#define MFMA16(a, b, c) __builtin_amdgcn_mfma_f32_16x16x32_bf16(a, b, c, 0, 0, 0)

__device__ __forceinline__ float sigf(float x)   { return 1.0f / (1.0f + __expf(-x)); }
__device__ __forceinline__ float tanh_f(float x) { return 1.0f - 2.0f / (__expf(2.0f * x) + 1.0f); }

__device__ __forceinline__ ushort bf16_rne(float v) {
    unsigned u = __float_as_uint(v);
    return (ushort)((u + 0x7FFFu + ((u >> 16) & 1u)) >> 16);
}
__device__ __forceinline__ void bsplit(float v, ushort& h, ushort& l) {
    h = bf16_rne(v);
    float fh = __uint_as_float(((unsigned)h) << 16);
    l = bf16_rne(v - fh);
}

// ---------------- init: cur <- x[:, 63, :, :] ----------------
__global__ void init_cur_k(const float* __restrict__ x, float* __restrict__ cur)
{
    int i   = blockIdx.x * 256 + threadIdx.x;   // 0 .. 524287
    int b   = i >> 13;
    int rem = i & 8191;
    cur[i] = x[(size_t)b * 524288 + 63 * 8192 + rem];
}

// ---------------- split hidden_intensity to bf16 hi/lo, once ----------------
__global__ void split_hi_k(const float* __restrict__ hi,
                           ushort* __restrict__ hi_hi, ushort* __restrict__ hi_lo)
{
    int i = blockIdx.x * 256 + threadIdx.x;     // 0 .. 2097151
    ushort h, l; bsplit(hi[i], h, l);
    hi_hi[i] = h; hi_lo[i] = l;
}

// ---------------- pack W1/W2/W3 into MFMA B-fragment order, once ------------
// B-frag (16x16x32): lane l holds B[k = (l>>4)*8 + j][col = l&15], j=0..7.
// wp1: [kt(8)][nt(8)][hsel(2)][lane(64)][j(8)]  (K=256: hs|hi, N=128)
// wp2: [kt(4)][nt(4)][hsel(2)][lane][j]         (K=128, N=64)
// wp3: [kt(2)][hsel(2)][lane][j]                (K=64,  N=16: cols 8..15 zero)
__global__ void pack_w_k(const float* __restrict__ W1, const float* __restrict__ W2,
                         const float* __restrict__ W3, ushort* __restrict__ wp1,
                         ushort* __restrict__ wp2, ushort* __restrict__ wp3)
{
    int i = blockIdx.x * 256 + threadIdx.x;
    if (i < 65536) {                       // W1 frags
        int fragid = i >> 9, lj = i & 511;
        int kt = fragid >> 4, nt = (fragid >> 1) & 7, hsel = fragid & 1;
        int l = lj >> 3, j = lj & 7;
        int k = kt * 32 + (l >> 4) * 8 + j;         // < 256
        int o = nt * 16 + (l & 15);                 // < 128
        float v = W1[o * 257 + k];
        ushort h, lo; bsplit(v, h, lo);
        wp1[i] = hsel ? lo : h;
    } else if (i < 65536 + 16384) {        // W2 frags
        int ii = i - 65536;
        int fragid = ii >> 9, lj = ii & 511;
        int kt = fragid >> 3, nt = (fragid >> 1) & 3, hsel = fragid & 1;
        int l = lj >> 3, j = lj & 7;
        int k = kt * 32 + (l >> 4) * 8 + j;         // < 128
        int o = nt * 16 + (l & 15);                 // < 64
        float v = W2[o * 128 + k];
        ushort h, lo; bsplit(v, h, lo);
        wp2[ii] = hsel ? lo : h;
    } else if (i < 65536 + 16384 + 2048) { // W3 frags
        int ii = i - 65536 - 16384;
        int fragid = ii >> 9, lj = ii & 511;
        int kt = fragid >> 1, hsel = fragid & 1;
        int l = lj >> 3, j = lj & 7;
        int k = kt * 32 + (l >> 4) * 8 + j;         // < 64
        int c = l & 15;
        float v = (c < 8) ? W3[c * 64 + k] : 0.0f;
        ushort h, lo; bsplit(v, h, lo);
        wp3[ii] = hsel ? lo : h;
    }
}

// ---------------- LSTM scan for one roll (round-1 proven structure) ----------
// 256 wgs x 512 thr. wg owns sequences q0..q0+3 for all 64 steps.
// Thread t owns gate row g=t: W_hh[g][*] in 128 VGPRs. h in LDS (broadcast).
// Epilogue writes h as split-bf16 pair for the MFMA MLP.
__global__ __launch_bounds__(512, 1) void lstm_roll_k(
    const float* __restrict__ cur, const float* __restrict__ W_ih,
    const float* __restrict__ W_hh, const float* __restrict__ b_ih,
    const float* __restrict__ b_hh, ushort* __restrict__ hs_hi,
    ushort* __restrict__ hs_lo)
{
    __shared__ __align__(16) float hL[4][128];   // h per sequence
    __shared__ float pre[4][512];                // gate preactivations

    const int t  = threadIdx.x;                  // gate row 0..511
    const int q0 = blockIdx.x * 4;

    float wih[8];
#pragma unroll
    for (int c = 0; c < 8; ++c) wih[c] = W_ih[t * 8 + c];
    const float bsum = b_ih[t] + b_hh[t];

    float w[128];
#pragma unroll
    for (int k = 0; k < 128; ++k) w[k] = W_hh[t * 128 + k];

    ((float*)hL)[t] = 0.0f;                      // 4*128 == 512 == blockDim
    float cc = 0.0f;
    const int s2 = t >> 7, j2 = t & 127;         // gate-math ownership (seq, h-elem)
    __syncthreads();

    for (int step = 0; step < 64; ++step) {
        // ---- phase 1: preact[g][s] = bsum + x.W_ih + h.W_hh ----
        const float* __restrict__ xr = cur + step * 8192 + q0 * 8;
        float a0 = bsum, a1 = bsum, a2 = bsum, a3 = bsum;
#pragma unroll
        for (int c = 0; c < 8; ++c) {
            float wc = wih[c];
            a0 += xr[c] * wc; a1 += xr[8 + c] * wc;
            a2 += xr[16 + c] * wc; a3 += xr[24 + c] * wc;
        }
#pragma unroll
        for (int jq = 0; jq < 32; ++jq) {
            float4 h0 = *(const float4*)&hL[0][jq * 4];
            float4 h1 = *(const float4*)&hL[1][jq * 4];
            float4 h2 = *(const float4*)&hL[2][jq * 4];
            float4 h3 = *(const float4*)&hL[3][jq * 4];
            float w0 = w[jq * 4 + 0], w1 = w[jq * 4 + 1];
            float w2 = w[jq * 4 + 2], w3 = w[jq * 4 + 3];
            a0 += h0.x * w0 + h0.y * w1 + h0.z * w2 + h0.w * w3;
            a1 += h1.x * w0 + h1.y * w1 + h1.z * w2 + h1.w * w3;
            a2 += h2.x * w0 + h2.y * w1 + h2.z * w2 + h2.w * w3;
            a3 += h3.x * w0 + h3.y * w1 + h3.z * w2 + h3.w * w3;
        }
        pre[0][t] = a0; pre[1][t] = a1; pre[2][t] = a2; pre[3][t] = a3;
        __syncthreads();

        // ---- phase 2: gates (torch order i,f,g,o), update c,h ----
        float pi = pre[s2][j2],       pf = pre[s2][128 + j2];
        float pg = pre[s2][256 + j2], po = pre[s2][384 + j2];
        cc = sigf(pf) * cc + sigf(pi) * tanh_f(pg);
        float hv = sigf(po) * tanh_f(cc);
        hL[s2][j2] = hv;   // safe: all phase-1 reads completed before prior barrier
        ushort hh, hl; bsplit(hv, hh, hl);
        size_t oidx = (size_t)(step * 1024 + q0 + s2) * 128 + j2;
        hs_hi[oidx] = hh; hs_lo[oidx] = hl;
        __syncthreads();
    }
}

// ---------------- MLP + head for one roll: split-bf16 MFMA ----------------
// 1024 wgs (b x 16 q-groups) x 256 thr (4 waves). wg owns 64 items (M=64).
// Wave w: GEMM1 cols [32w,32w+32), GEMM2 cols [16w,16w+16), GEMM3 rows [16w,16w+16).
// A-frag: lane l = row (l&15), k=(l>>4)*8+j.  C/D: col=l&15, row=(l>>4)*4+reg.
__global__ __launch_bounds__(256, 3) void mlp_mfma_k(
    const ushort* __restrict__ hs_hi, const ushort* __restrict__ hs_lo,
    const ushort* __restrict__ hi_hi, const ushort* __restrict__ hi_lo,
    const float* __restrict__ r, int jstep,
    const ushort* __restrict__ wp1, const ushort* __restrict__ wp2,
    const ushort* __restrict__ wp3,
    const float* __restrict__ W1, const float* __restrict__ b1,
    const float* __restrict__ b2, const float* __restrict__ b3,
    const float* __restrict__ Wf, const float* __restrict__ bfp,
    float* __restrict__ cur, float* __restrict__ out)
{
    __shared__ __align__(16) ushort h1f[16384];   // [hsel(2)][kt(4)][mt(4)][lane][8]  32KB
    __shared__ __align__(16) ushort h2f[8192];    // [hsel(2)][kt(2)][mt(4)][lane][8]  16KB

    const int t = threadIdx.x;
    const int w = t >> 6, l = t & 63;
    const int lrow = l & 15, lk = l >> 4;
    const int b = blockIdx.x >> 4;
    const int qb = (blockIdx.x & 15) * 64;
    const float rb = r[b * 4 + jstep];

    // ================= GEMM1: h1 = relu([hs|hi|r] @ W1^T + b1) =================
    f32x4 acc[4][2];
#pragma unroll
    for (int nt = 0; nt < 2; ++nt) {
        int col = w * 32 + nt * 16 + lrow;
        float bias = b1[col] + rb * W1[col * 257 + 256];   // fold r-column + b1 (fp32)
#pragma unroll
        for (int mt = 0; mt < 4; ++mt)
            acc[mt][nt] = (f32x4){bias, bias, bias, bias};
    }

#pragma unroll 2
    for (int kt = 0; kt < 8; ++kt) {
        short8 a_hi[4], a_lo[4];
#pragma unroll
        for (int mt = 0; mt < 4; ++mt) {
            int q = qb + mt * 16 + lrow;
            if (kt < 4) {
                size_t addr = (size_t)(b * 1024 + q) * 128 + kt * 32 + lk * 8;
                a_hi[mt] = *(const short8*)(hs_hi + addr);
                a_lo[mt] = *(const short8*)(hs_lo + addr);
            } else {
                size_t addr = (size_t)(b * 256 + (q >> 2)) * 128 + (kt - 4) * 32 + lk * 8;
                a_hi[mt] = *(const short8*)(hi_hi + addr);
                a_lo[mt] = *(const short8*)(hi_lo + addr);
            }
        }
#pragma unroll
        for (int nt = 0; nt < 2; ++nt) {
            int fb = ((kt * 8 + (w * 2 + nt)) * 2) * 512 + l * 8;
            short8 b_hi = *(const short8*)(wp1 + fb);
            short8 b_lo = *(const short8*)(wp1 + fb + 512);
#pragma unroll
            for (int mt = 0; mt < 4; ++mt) {
                acc[mt][nt] = MFMA16(a_hi[mt], b_hi, acc[mt][nt]);
                acc[mt][nt] = MFMA16(a_hi[mt], b_lo, acc[mt][nt]);
                acc[mt][nt] = MFMA16(a_lo[mt], b_hi, acc[mt][nt]);
            }
        }
    }

    // epilogue1: relu + split -> h1 frag zone (kt2 == w for this wave's cols)
#pragma unroll
    for (int mt = 0; mt < 4; ++mt)
#pragma unroll
        for (int nt = 0; nt < 2; ++nt)
#pragma unroll
            for (int reg = 0; reg < 4; ++reg) {
                float v = fmaxf(acc[mt][nt][reg], 0.0f);
                ushort vh, vl; bsplit(v, vh, vl);
                int lp = lk * 4 + reg + 16 * (nt * 2 + (lrow >> 3));
                int jj = lrow & 7;
                h1f[((0 * 4 + w) * 4 + mt) * 512 + lp * 8 + jj] = vh;
                h1f[((1 * 4 + w) * 4 + mt) * 512 + lp * 8 + jj] = vl;
            }
    __syncthreads();

    // ================= GEMM2: h2 = relu(h1 @ W2^T + b2), cols 16w..16w+15 =====
    f32x4 acc2[4];
    {
        float bias = b2[16 * w + lrow];
#pragma unroll
        for (int mt = 0; mt < 4; ++mt)
            acc2[mt] = (f32x4){bias, bias, bias, bias};
    }
#pragma unroll
    for (int kt = 0; kt < 4; ++kt) {
        int fb = ((kt * 4 + w) * 2) * 512 + l * 8;
        short8 b_hi = *(const short8*)(wp2 + fb);
        short8 b_lo = *(const short8*)(wp2 + fb + 512);
#pragma unroll
        for (int mt = 0; mt < 4; ++mt) {
            short8 a_hi = *(const short8*)&h1f[((0 * 4 + kt) * 4 + mt) * 512 + l * 8];
            short8 a_lo = *(const short8*)&h1f[((1 * 4 + kt) * 4 + mt) * 512 + l * 8];
            acc2[mt] = MFMA16(a_hi, b_hi, acc2[mt]);
            acc2[mt] = MFMA16(a_hi, b_lo, acc2[mt]);
            acc2[mt] = MFMA16(a_lo, b_hi, acc2[mt]);
        }
    }
    // epilogue2: relu + split -> h2 frag zone
#pragma unroll
    for (int mt = 0; mt < 4; ++mt)
#pragma unroll
        for (int reg = 0; reg < 4; ++reg) {
            float v = fmaxf(acc2[mt][reg], 0.0f);
            ushort vh, vl; bsplit(v, vl == vl ? vh : vh, vl);  // no-op guard removed below
            bsplit(v, vh, vl);
            int col2 = 16 * w + lrow;
            int kt3 = col2 >> 5;
            int lp = lk * 4 + reg + 16 * ((col2 >> 3) & 3);
            int jj = col2 & 7;
            h2f[((0 * 2 + kt3) * 4 + mt) * 512 + lp * 8 + jj] = vh;
            h2f[((1 * 2 + kt3) * 4 + mt) * 512 + lp * 8 + jj] = vl;
        }
    __syncthreads();

    // ================= GEMM3: pr = h2 @ W3^T + b3, wave w does rows 16w.. =====
    f32x4 acc3 = (f32x4){0.0f, 0.0f, 0.0f, 0.0f};
#pragma unroll
    for (int kt = 0; kt < 2; ++kt) {
        short8 a_hi = *(const short8*)&h2f[((0 * 2 + kt) * 4 + w) * 512 + l * 8];
        short8 a_lo = *(const short8*)&h2f[((1 * 2 + kt) * 4 + w) * 512 + l * 8];
        int fb = (kt * 2) * 512 + l * 8;
        short8 b_hi = *(const short8*)(wp3 + fb);
        short8 b_lo = *(const short8*)(wp3 + fb + 512);
        acc3 = MFMA16(a_hi, b_hi, acc3);
        acc3 = MFMA16(a_hi, b_lo, acc3);
        acc3 = MFMA16(a_lo, b_hi, acc3);
    }

    // epilogue3: cur <- pr (raw); head: sum relu(pr)*Wf over C, then over Ct
    const int c = lrow;
    const float b3v = (c < 8) ? b3[c] : 0.0f;
    const float wfv = (c < 8) ? Wf[c] : 0.0f;
    float fr[4];
#pragma unroll
    for (int reg = 0; reg < 4; ++reg) {
        float pr = acc3[reg] + b3v;
        if (c < 8) {
            int row = 16 * w + lk * 4 + reg;
            cur[(size_t)(b * 1024 + qb + row) * 8 + c] = pr;
        }
        fr[reg] = (c < 8) ? fmaxf(pr, 0.0f) * wfv : 0.0f;
    }
#pragma unroll
    for (int reg = 0; reg < 4; ++reg) {
        fr[reg] += __shfl_xor(fr[reg], 1);
        fr[reg] += __shfl_xor(fr[reg], 2);
        fr[reg] += __shfl_xor(fr[reg], 4);
    }
    if ((l & 15) == 0) {
        int n = (qb + 16 * w + lk * 4) >> 2;
        float v = fr[0] + fr[1] + fr[2] + fr[3] + 4.0f * bfp[0];
        out[(size_t)(b * 256 + n) * 4 + jstep] = v;
    }
}

extern "C" void kernel_launch(void* const* d_in, const int* in_sizes, int n_in,
                              void* d_out, int out_size, void* d_ws, size_t ws_size,
                              hipStream_t stream)
{
    const float* x   = (const float*)d_in[0];
    const float* hi  = (const float*)d_in[1];
    const float* r   = (const float*)d_in[2];
    const float* Wih = (const float*)d_in[3];
    const float* Whh = (const float*)d_in[4];
    const float* bih = (const float*)d_in[5];
    const float* bhh = (const float*)d_in[6];
    const float* W1  = (const float*)d_in[7];
    const float* b1  = (const float*)d_in[8];
    const float* W2  = (const float*)d_in[9];
    const float* b2  = (const float*)d_in[10];
    const float* W3  = (const float*)d_in[11];
    const float* b3  = (const float*)d_in[12];
    const float* Wf  = (const float*)d_in[13];
    const float* bf  = (const float*)d_in[14];
    float* out = (float*)d_out;

    float*  cur   = (float*)d_ws;                      // 524288 f32   (2 MB)
    ushort* hs_hi = (ushort*)(cur + 524288);           // 8388608 us  (16 MB)
    ushort* hs_lo = hs_hi + 8388608;                   // 16 MB
    ushort* hi_hi = hs_lo + 8388608;                   // 2097152 us   (4 MB)
    ushort* hi_lo = hi_hi + 2097152;                   // 4 MB
    ushort* wp1   = hi_lo + 2097152;                   // 65536 us
    ushort* wp2   = wp1 + 65536;                       // 16384 us
    ushort* wp3   = wp2 + 16384;                       // 2048 us

    init_cur_k<<<2048, 256, 0, stream>>>(x, cur);
    split_hi_k<<<8192, 256, 0, stream>>>(hi, hi_hi, hi_lo);
    pack_w_k<<<328, 256, 0, stream>>>(W1, W2, W3, wp1, wp2, wp3);
    for (int j = 0; j < 4; ++j) {
        lstm_roll_k<<<256, 512, 0, stream>>>(cur, Wih, Whh, bih, bhh, hs_hi, hs_lo);
        mlp_mfma_k<<<1024, 256, 0, stream>>>(hs_hi, hs_lo, hi_hi, hi_lo, r, j,
                                             wp1, wp2, wp3, W1, b1, b2, b3,
                                             Wf, bf, cur, out);
    }
}

// Round 4
// 805.783 us; speedup vs baseline: 3.1129x; 1.2529x over previous
//
#include <hip/hip_runtime.h>
#include <hip/hip_bf16.h>

// B=64 (LSTM time axis via torch batch_first quirk), L=64 (only col 63 used),
// N=256, C=8, Ct=4 -> NQ=1024 sequences, H=128, 4H=512, RH1=128, RH2=64, S=4.
//
// Everything matmul-shaped runs as split-bf16 MFMA: f = hi + lo (two bf16),
// product via 3 MFMAs (hi*hi + hi*lo + lo*hi), fp32 accum -> ~2^-17 rel error.

typedef __attribute__((ext_vector_type(8))) short short8;   // 8 bf16 in 4 VGPRs
typedef __attribute__((ext_vector_type(4))) float f32x4;

#define MFMA16(a, b, c) __builtin_amdgcn_mfma_f32_16x16x32_bf16(a, b, c, 0, 0, 0)

__device__ __forceinline__ float sigf(float x)   { return 1.0f / (1.0f + __expf(-x)); }
__device__ __forceinline__ float tanh_f(float x) { return 1.0f - 2.0f / (__expf(2.0f * x) + 1.0f); }

__device__ __forceinline__ ushort bf16_rne(float v) {
    unsigned u = __float_as_uint(v);
    return (ushort)((u + 0x7FFFu + ((u >> 16) & 1u)) >> 16);
}
__device__ __forceinline__ void bsplit(float v, ushort& h, ushort& l) {
    h = bf16_rne(v);
    float fh = __uint_as_float(((unsigned)h) << 16);
    l = bf16_rne(v - fh);
}

// ---------------- init: cur(hi/lo) <- x[:, 63, :, :] ----------------
__global__ void init_cur_k(const float* __restrict__ x,
                           ushort* __restrict__ cur_hi, ushort* __restrict__ cur_lo)
{
    int i   = blockIdx.x * 256 + threadIdx.x;   // 0 .. 524287
    int b   = i >> 13;
    int rem = i & 8191;
    ushort h, l; bsplit(x[(size_t)b * 524288 + 63 * 8192 + rem], h, l);
    cur_hi[i] = h; cur_lo[i] = l;
}

// ---------------- split hidden_intensity to bf16 hi/lo, once ----------------
__global__ void split_hi_k(const float* __restrict__ hi,
                           ushort* __restrict__ hi_hi, ushort* __restrict__ hi_lo)
{
    int i = blockIdx.x * 256 + threadIdx.x;     // 0 .. 2097151
    ushort h, l; bsplit(hi[i], h, l);
    hi_hi[i] = h; hi_lo[i] = l;
}

// ---------------- pack W1/W2/W3 into MFMA B-fragment order, once ------------
// B-frag (16x16x32): lane l holds B[k = (l>>4)*8 + j][col = l&15], j=0..7.
__global__ void pack_w_k(const float* __restrict__ W1, const float* __restrict__ W2,
                         const float* __restrict__ W3, ushort* __restrict__ wp1,
                         ushort* __restrict__ wp2, ushort* __restrict__ wp3)
{
    int i = blockIdx.x * 256 + threadIdx.x;
    if (i < 65536) {                       // W1 frags [kt8][nt8][hsel2][512]
        int fragid = i >> 9, lj = i & 511;
        int kt = fragid >> 4, nt = (fragid >> 1) & 7, hsel = fragid & 1;
        int l = lj >> 3, j = lj & 7;
        int k = kt * 32 + (l >> 4) * 8 + j;
        int o = nt * 16 + (l & 15);
        ushort h, lo; bsplit(W1[o * 257 + k], h, lo);
        wp1[i] = hsel ? lo : h;
    } else if (i < 65536 + 16384) {        // W2 frags [kt4][nt4][hsel2][512]
        int ii = i - 65536;
        int fragid = ii >> 9, lj = ii & 511;
        int kt = fragid >> 3, nt = (fragid >> 1) & 3, hsel = fragid & 1;
        int l = lj >> 3, j = lj & 7;
        int k = kt * 32 + (l >> 4) * 8 + j;
        int o = nt * 16 + (l & 15);
        ushort h, lo; bsplit(W2[o * 128 + k], h, lo);
        wp2[ii] = hsel ? lo : h;
    } else if (i < 65536 + 16384 + 2048) { // W3 frags [kt2][hsel2][512]
        int ii = i - 65536 - 16384;
        int fragid = ii >> 9, lj = ii & 511;
        int kt = fragid >> 1, hsel = fragid & 1;
        int l = lj >> 3, j = lj & 7;
        int k = kt * 32 + (l >> 4) * 8 + j;
        int c = l & 15;
        float v = (c < 8) ? W3[c * 64 + k] : 0.0f;
        ushort h, lo; bsplit(v, h, lo);
        wp3[ii] = hsel ? lo : h;
    }
}

// ---------------- pack [W_hh | W_ih] into B-frags, K=160 (kt=4 is x, padded) --
// wpB layout: [kt(5)][nt(32)][hsel(2)][512 ushorts]; col = nt*16 + (l&15) = gate row.
__global__ void pack_wB_k(const float* __restrict__ W_hh, const float* __restrict__ W_ih,
                          ushort* __restrict__ wpB)
{
    int i = blockIdx.x * 256 + threadIdx.x;     // 0 .. 163839
    int frag = i >> 9, lj = i & 511;
    int kt = frag >> 6, nt = (frag >> 1) & 31, hsel = frag & 1;
    int l = lj >> 3, j = lj & 7;
    int k = kt * 32 + (l >> 4) * 8 + j;         // 0..159
    int col = nt * 16 + (l & 15);               // gate row 0..511
    float v = (k < 128) ? W_hh[col * 128 + k]
            : ((k < 136) ? W_ih[col * 8 + (k - 128)] : 0.0f);
    ushort h, lo; bsplit(v, h, lo);
    wpB[i] = hsel ? lo : h;
}

// ---------------- LSTM scan, split-bf16 MFMA ----------------
// 64 wgs x 512 thr (8 waves). wg owns 16 sequences (one M-tile) for 64 steps.
// Wave w computes gate tiles nt={w,8+w,16+w,24+w} -> same 16 hidden cols of all
// 4 gates -> gate math fully in-lane (C/D: col=l&15, row=(l>>4)*4+reg).
// h passes step-to-step via double-buffered LDS frag zone (s-major layout:
// plane(hsel,kt) offset = s*32 + ((j&31)>>3)*8 + (j&7)); zone dumped to hs_f.
__global__ __launch_bounds__(512, 2) void lstm_mfma_k(
    const ushort* __restrict__ cur_hi, const ushort* __restrict__ cur_lo,
    const ushort* __restrict__ wpB, const float* __restrict__ b_ih,
    const float* __restrict__ b_hh, ushort* __restrict__ hs_f)
{
    __shared__ __align__(16) ushort zone[2][2][4][512];   // [buf][hsel][kt][...] 16KB

    const int t  = threadIdx.x;
    const int w  = t >> 6, l = t & 63;
    const int li = l & 15, lk = l >> 4;
    const int qblk = blockIdx.x;
    const int q0   = qblk * 16;

    // load this wave's B-frags: 4 gates x 5 kt x {hi,lo} = 160 VGPRs
    short8 bh[4][5], bl[4][5];
#pragma unroll
    for (int g = 0; g < 4; ++g)
#pragma unroll
        for (int kt = 0; kt < 5; ++kt) {
            size_t fb = ((size_t)((kt * 32 + g * 8 + w) * 2)) * 512 + l * 8;
            bh[g][kt] = *(const short8*)(wpB + fb);
            bl[g][kt] = *(const short8*)(wpB + fb + 512);
        }
    float bsum[4];
#pragma unroll
    for (int g = 0; g < 4; ++g) {
        int gg = g * 128 + w * 16 + li;
        bsum[g] = b_ih[gg] + b_hh[gg];
    }

    ((uint4*)&zone[0][0][0][0])[t] = make_uint4(0, 0, 0, 0);   // h_0 = 0 (buf 0)
    float cc[4] = {0.0f, 0.0f, 0.0f, 0.0f};
    __syncthreads();

    const int ktw  = w >> 1;                         // this wave's j-plane
    const int qq   = (w & 1) * 2 + (li >> 3);
    const int jjj  = li & 7;
    const int roff = li * 32 + lk * 8;               // A-frag read offset in plane

#pragma unroll 2
    for (int step = 0; step < 64; ++step) {
        const int p = step & 1, pn = p ^ 1;

        // x A-frag: lanes use row li; k>=136 columns have zero B -> value moot
        const size_t xb = ((size_t)step * 1024 + q0 + li) * 8;
        const short8 xh = *(const short8*)(cur_hi + xb);
        const short8 xl = *(const short8*)(cur_lo + xb);

        f32x4 acc[4];
#pragma unroll
        for (int g = 0; g < 4; ++g)
            acc[g] = (f32x4){bsum[g], bsum[g], bsum[g], bsum[g]};

#pragma unroll
        for (int kt = 0; kt < 4; ++kt) {
            short8 ah = *(const short8*)&zone[p][0][kt][roff];
            short8 al = *(const short8*)&zone[p][1][kt][roff];
#pragma unroll
            for (int g = 0; g < 4; ++g) {
                acc[g] = MFMA16(ah, bh[g][kt], acc[g]);
                acc[g] = MFMA16(ah, bl[g][kt], acc[g]);
                acc[g] = MFMA16(al, bh[g][kt], acc[g]);
            }
        }
#pragma unroll
        for (int g = 0; g < 4; ++g) {
            acc[g] = MFMA16(xh, bh[g][4], acc[g]);
            acc[g] = MFMA16(xh, bl[g][4], acc[g]);
            acc[g] = MFMA16(xl, bh[g][4], acc[g]);
        }

        // gates (torch order i,f,g,o) fully in-register; write h frags -> buf pn
#pragma unroll
        for (int r = 0; r < 4; ++r) {
            float pi = acc[0][r], pf = acc[1][r], pg = acc[2][r], po = acc[3][r];
            cc[r] = sigf(pf) * cc[r] + sigf(pi) * tanh_f(pg);
            float hv = sigf(po) * tanh_f(cc[r]);
            ushort hh, hl; bsplit(hv, hh, hl);
            int off = (lk * 4 + r) * 32 + qq * 8 + jjj;
            zone[pn][0][ktw][off] = hh;
            zone[pn][1][ktw][off] = hl;
        }
        __syncthreads();

        // dump buf pn (h after this step) to hs_f, fully coalesced
        uint4 v = ((const uint4*)&zone[pn][0][0][0])[t];
        ((uint4*)hs_f)[(size_t)(step * 64 + qblk) * 512 + t] = v;
    }
}

// ---------------- MLP + head for one roll: split-bf16 MFMA ----------------
// 1024 wgs (b x 16 q-groups) x 256 thr (4 waves). wg owns 64 items (M=64).
__global__ __launch_bounds__(256, 3) void mlp_mfma_k(
    const ushort* __restrict__ hs_f,
    const ushort* __restrict__ hi_hi, const ushort* __restrict__ hi_lo,
    const float* __restrict__ r, int jstep,
    const ushort* __restrict__ wp1, const ushort* __restrict__ wp2,
    const ushort* __restrict__ wp3,
    const float* __restrict__ W1, const float* __restrict__ b1,
    const float* __restrict__ b2, const float* __restrict__ b3,
    const float* __restrict__ Wf, const float* __restrict__ bfp,
    ushort* __restrict__ cur_hi, ushort* __restrict__ cur_lo,
    float* __restrict__ out)
{
    __shared__ __align__(16) ushort h1f[16384];   // [hsel2][kt4][mt4][lane][8]
    __shared__ __align__(16) ushort h2f[8192];    // [hsel2][kt2][mt4][lane][8]

    const int t = threadIdx.x;
    const int w = t >> 6, l = t & 63;
    const int lrow = l & 15, lk = l >> 4;
    const int b = blockIdx.x >> 4;
    const int qb = (blockIdx.x & 15) * 64;
    const float rb = r[b * 4 + jstep];

    // ================= GEMM1: h1 = relu([hs|hi|r] @ W1^T + b1) =================
    f32x4 acc[4][2];
#pragma unroll
    for (int nt = 0; nt < 2; ++nt) {
        int col = w * 32 + nt * 16 + lrow;
        float bias = b1[col] + rb * W1[col * 257 + 256];   // fold r-col + b1 (fp32)
#pragma unroll
        for (int mt = 0; mt < 4; ++mt)
            acc[mt][nt] = (f32x4){bias, bias, bias, bias};
    }

#pragma unroll 2
    for (int kt = 0; kt < 8; ++kt) {
        short8 a_hi[4], a_lo[4];
#pragma unroll
        for (int mt = 0; mt < 4; ++mt) {
            if (kt < 4) {   // hs part: frag-zone layout from lstm_mfma_k
                size_t base = ((size_t)b * 64 + (qb >> 4) + mt) * 4096;
                a_hi[mt] = *(const short8*)(hs_f + base + kt * 512 + lrow * 32 + lk * 8);
                a_lo[mt] = *(const short8*)(hs_f + base + 2048 + kt * 512 + lrow * 32 + lk * 8);
            } else {        // hidden_intensity part: row-major is frag-friendly
                int q = qb + mt * 16 + lrow;
                size_t addr = (size_t)(b * 256 + (q >> 2)) * 128 + (kt - 4) * 32 + lk * 8;
                a_hi[mt] = *(const short8*)(hi_hi + addr);
                a_lo[mt] = *(const short8*)(hi_lo + addr);
            }
        }
#pragma unroll
        for (int nt = 0; nt < 2; ++nt) {
            int fb = ((kt * 8 + (w * 2 + nt)) * 2) * 512 + l * 8;
            short8 b_hi = *(const short8*)(wp1 + fb);
            short8 b_lo = *(const short8*)(wp1 + fb + 512);
#pragma unroll
            for (int mt = 0; mt < 4; ++mt) {
                acc[mt][nt] = MFMA16(a_hi[mt], b_hi, acc[mt][nt]);
                acc[mt][nt] = MFMA16(a_hi[mt], b_lo, acc[mt][nt]);
                acc[mt][nt] = MFMA16(a_lo[mt], b_hi, acc[mt][nt]);
            }
        }
    }

    // epilogue1: relu + split -> h1 frag zone
#pragma unroll
    for (int mt = 0; mt < 4; ++mt)
#pragma unroll
        for (int nt = 0; nt < 2; ++nt)
#pragma unroll
            for (int reg = 0; reg < 4; ++reg) {
                float v = fmaxf(acc[mt][nt][reg], 0.0f);
                ushort vh, vl; bsplit(v, vh, vl);
                int lp = lk * 4 + reg + 16 * (nt * 2 + (lrow >> 3));
                int jj = lrow & 7;
                h1f[((0 * 4 + w) * 4 + mt) * 512 + lp * 8 + jj] = vh;
                h1f[((1 * 4 + w) * 4 + mt) * 512 + lp * 8 + jj] = vl;
            }
    __syncthreads();

    // ================= GEMM2: h2 = relu(h1 @ W2^T + b2), cols 16w..16w+15 =====
    f32x4 acc2[4];
    {
        float bias = b2[16 * w + lrow];
#pragma unroll
        for (int mt = 0; mt < 4; ++mt)
            acc2[mt] = (f32x4){bias, bias, bias, bias};
    }
#pragma unroll
    for (int kt = 0; kt < 4; ++kt) {
        int fb = ((kt * 4 + w) * 2) * 512 + l * 8;
        short8 b_hi = *(const short8*)(wp2 + fb);
        short8 b_lo = *(const short8*)(wp2 + fb + 512);
#pragma unroll
        for (int mt = 0; mt < 4; ++mt) {
            short8 a_hi = *(const short8*)&h1f[((0 * 4 + kt) * 4 + mt) * 512 + l * 8];
            short8 a_lo = *(const short8*)&h1f[((1 * 4 + kt) * 4 + mt) * 512 + l * 8];
            acc2[mt] = MFMA16(a_hi, b_hi, acc2[mt]);
            acc2[mt] = MFMA16(a_hi, b_lo, acc2[mt]);
            acc2[mt] = MFMA16(a_lo, b_hi, acc2[mt]);
        }
    }
    // epilogue2: relu + split -> h2 frag zone
#pragma unroll
    for (int mt = 0; mt < 4; ++mt)
#pragma unroll
        for (int reg = 0; reg < 4; ++reg) {
            float v = fmaxf(acc2[mt][reg], 0.0f);
            ushort vh, vl; bsplit(v, vh, vl);
            int col2 = 16 * w + lrow;
            int kt3 = col2 >> 5;
            int lp = lk * 4 + reg + 16 * ((col2 >> 3) & 3);
            int jj = col2 & 7;
            h2f[((0 * 2 + kt3) * 4 + mt) * 512 + lp * 8 + jj] = vh;
            h2f[((1 * 2 + kt3) * 4 + mt) * 512 + lp * 8 + jj] = vl;
        }
    __syncthreads();

    // ================= GEMM3: pr = h2 @ W3^T + b3, wave w does rows 16w.. =====
    f32x4 acc3 = (f32x4){0.0f, 0.0f, 0.0f, 0.0f};
#pragma unroll
    for (int kt = 0; kt < 2; ++kt) {
        short8 a_hi = *(const short8*)&h2f[((0 * 2 + kt) * 4 + w) * 512 + l * 8];
        short8 a_lo = *(const short8*)&h2f[((1 * 2 + kt) * 4 + w) * 512 + l * 8];
        int fb = (kt * 2) * 512 + l * 8;
        short8 b_hi = *(const short8*)(wp3 + fb);
        short8 b_lo = *(const short8*)(wp3 + fb + 512);
        acc3 = MFMA16(a_hi, b_hi, acc3);
        acc3 = MFMA16(a_hi, b_lo, acc3);
        acc3 = MFMA16(a_lo, b_hi, acc3);
    }

    // epilogue3: cur(hi/lo) <- pr (raw, split); head: sum relu(pr)*Wf over C, Ct
    const int c = lrow;
    const float b3v = (c < 8) ? b3[c] : 0.0f;
    const float wfv = (c < 8) ? Wf[c] : 0.0f;
    float fr[4];
#pragma unroll
    for (int reg = 0; reg < 4; ++reg) {
        float pr = acc3[reg] + b3v;
        if (c < 8) {
            int row = 16 * w + lk * 4 + reg;
            size_t idx = ((size_t)(b * 1024 + qb + row)) * 8 + c;
            ushort ph, plo; bsplit(pr, ph, plo);
            cur_hi[idx] = ph; cur_lo[idx] = plo;
        }
        fr[reg] = (c < 8) ? fmaxf(pr, 0.0f) * wfv : 0.0f;
    }
#pragma unroll
    for (int reg = 0; reg < 4; ++reg) {
        fr[reg] += __shfl_xor(fr[reg], 1);
        fr[reg] += __shfl_xor(fr[reg], 2);
        fr[reg] += __shfl_xor(fr[reg], 4);
    }
    if ((l & 15) == 0) {
        int n = (qb + 16 * w + lk * 4) >> 2;
        float v = fr[0] + fr[1] + fr[2] + fr[3] + 4.0f * bfp[0];
        out[(size_t)(b * 256 + n) * 4 + jstep] = v;
    }
}

extern "C" void kernel_launch(void* const* d_in, const int* in_sizes, int n_in,
                              void* d_out, int out_size, void* d_ws, size_t ws_size,
                              hipStream_t stream)
{
    const float* x   = (const float*)d_in[0];
    const float* hi  = (const float*)d_in[1];
    const float* r   = (const float*)d_in[2];
    const float* Wih = (const float*)d_in[3];
    const float* Whh = (const float*)d_in[4];
    const float* bih = (const float*)d_in[5];
    const float* bhh = (const float*)d_in[6];
    const float* W1  = (const float*)d_in[7];
    const float* b1  = (const float*)d_in[8];
    const float* W2  = (const float*)d_in[9];
    const float* b2  = (const float*)d_in[10];
    const float* W3  = (const float*)d_in[11];
    const float* b3  = (const float*)d_in[12];
    const float* Wf  = (const float*)d_in[13];
    const float* bf  = (const float*)d_in[14];
    float* out = (float*)d_out;

    ushort* cur_hi = (ushort*)d_ws;                    // 524288
    ushort* cur_lo = cur_hi + 524288;                  // 524288
    ushort* hs_f   = cur_lo + 524288;                  // 16777216 (32 MB)
    ushort* hi_hi  = hs_f + 16777216;                  // 2097152
    ushort* hi_lo  = hi_hi + 2097152;                  // 2097152
    ushort* wp1    = hi_lo + 2097152;                  // 65536
    ushort* wp2    = wp1 + 65536;                      // 16384
    ushort* wp3    = wp2 + 16384;                      // 2048
    ushort* wpB    = wp3 + 2048;                       // 163840

    init_cur_k<<<2048, 256, 0, stream>>>(x, cur_hi, cur_lo);
    split_hi_k<<<8192, 256, 0, stream>>>(hi, hi_hi, hi_lo);
    pack_w_k<<<328, 256, 0, stream>>>(W1, W2, W3, wp1, wp2, wp3);
    pack_wB_k<<<640, 256, 0, stream>>>(Whh, Wih, wpB);
    for (int j = 0; j < 4; ++j) {
        lstm_mfma_k<<<64, 512, 0, stream>>>(cur_hi, cur_lo, wpB, bih, bhh, hs_f);
        mlp_mfma_k<<<1024, 256, 0, stream>>>(hs_f, hi_hi, hi_lo, r, j,
                                             wp1, wp2, wp3, W1, b1, b2, b3,
                                             Wf, bf, cur_hi, cur_lo, out);
    }
}

// Round 5
// 666.221 us; speedup vs baseline: 3.7650x; 1.2095x over previous
//
#include <hip/hip_runtime.h>
#include <hip/hip_bf16.h>

// B=64 (LSTM time axis via torch batch_first quirk), L=64 (only col 63 used),
// N=256, C=8, Ct=4 -> NQ=1024 sequences, H=128, 4H=512, RH1=128, RH2=64, S=4.
//
// All matmuls use STACKED split-bf16 MFMA: f = hi + lo (two bf16); stack
// [A_hi|A_lo] along K against [B_hi;B_lo] -> ONE mfma computes all 4 cross
// terms in fp32 accum (~2^-17 rel error, fp32-like), at 1x MFMA cost per
// stacked-K element pair.

typedef __attribute__((ext_vector_type(8))) short short8;   // 8 bf16 in 4 VGPRs
typedef __attribute__((ext_vector_type(4))) float f32x4;

#define MFMA16(a, b, c) __builtin_amdgcn_mfma_f32_16x16x32_bf16(a, b, c, 0, 0, 0)

__device__ __forceinline__ float sigf(float x)   { return 1.0f / (1.0f + __expf(-x)); }
__device__ __forceinline__ float tanh_f(float x) { return 1.0f - 2.0f / (__expf(2.0f * x) + 1.0f); }

__device__ __forceinline__ ushort bf16_rne(float v) {
    unsigned u = __float_as_uint(v);
    return (ushort)((u + 0x7FFFu + ((u >> 16) & 1u)) >> 16);
}
__device__ __forceinline__ void bsplit(float v, ushort& h, ushort& l) {
    h = bf16_rne(v);
    float fh = __uint_as_float(((unsigned)h) << 16);
    l = bf16_rne(v - fh);
}

// ---------------- init: cur(hi/lo) <- x[:, 63, :, :] ----------------
__global__ void init_cur_k(const float* __restrict__ x,
                           ushort* __restrict__ cur_hi, ushort* __restrict__ cur_lo)
{
    int i   = blockIdx.x * 256 + threadIdx.x;   // 0 .. 524287
    int b   = i >> 13;
    int rem = i & 8191;
    ushort h, l; bsplit(x[(size_t)b * 524288 + 63 * 8192 + rem], h, l);
    cur_hi[i] = h; cur_lo[i] = l;
}

// ---------------- split hidden_intensity to bf16 hi/lo, once ----------------
__global__ void split_hi_k(const float* __restrict__ hi,
                           ushort* __restrict__ hi_hi, ushort* __restrict__ hi_lo)
{
    int i = blockIdx.x * 256 + threadIdx.x;     // 0 .. 2097151
    ushort h, l; bsplit(hi[i], h, l);
    hi_hi[i] = h; hi_lo[i] = l;
}

// ---------------- pack W1/W2/W3 into stacked-K MFMA B-frags, once ------------
// B-frag (16x16x32): lane l holds B[k = (l>>4)*8 + j][col = l&15], j=0..7.
// Stacked K' ordering matches A planes: [src_hi(sec0)|src_lo(sec0)|hi(sec1)|lo(sec1)].
__global__ void pack_w_k(const float* __restrict__ W1, const float* __restrict__ W2,
                         const float* __restrict__ W3, ushort* __restrict__ wp1,
                         ushort* __restrict__ wp2, ushort* __restrict__ wp3)
{
    int i = blockIdx.x * 256 + threadIdx.x;
    if (i < 65536) {                       // wp1 [kt16][nt8][512]; K'=512 over [hs|hi]
        int fragid = i >> 9, lj = i & 511;
        int kt = fragid >> 3, nt = fragid & 7;
        int l = lj >> 3, j = lj & 7;
        int klocal = (l >> 4) * 8 + j;
        int k = (kt >> 3) * 128 + (kt & 3) * 32 + klocal;   // source k (0..255)
        int hsel = (kt >> 2) & 1;
        int o = nt * 16 + (l & 15);
        ushort h, lo; bsplit(W1[o * 257 + k], h, lo);
        wp1[i] = hsel ? lo : h;
    } else if (i < 65536 + 16384) {        // wp2 [kt8][nt4][512]; K'=256
        int ii = i - 65536;
        int fragid = ii >> 9, lj = ii & 511;
        int kt = fragid >> 2, nt = fragid & 3;
        int l = lj >> 3, j = lj & 7;
        int klocal = (l >> 4) * 8 + j;
        int k = (kt & 3) * 32 + klocal;                     // 0..127
        int hsel = (kt >> 2) & 1;
        int o = nt * 16 + (l & 15);
        ushort h, lo; bsplit(W2[o * 128 + k], h, lo);
        wp2[ii] = hsel ? lo : h;
    } else if (i < 65536 + 16384 + 2048) { // wp3 [kt4][512]; K'=128
        int ii = i - 65536 - 16384;
        int kt = ii >> 9, lj = ii & 511;
        int l = lj >> 3, j = lj & 7;
        int klocal = (l >> 4) * 8 + j;
        int k = (kt & 1) * 32 + klocal;                     // 0..63
        int hsel = kt >> 1;
        int c = l & 15;
        float v = (c < 8) ? W3[c * 64 + k] : 0.0f;
        ushort h, lo; bsplit(v, h, lo);
        wp3[ii] = hsel ? lo : h;
    }
}

// ---------------- pack [W_hh(stacked) | W_ih(stacked)] B-frags, once ---------
// wpB [kt(9)][ntile(32)][512]: kt 0..3 = Whh_hi, 4..7 = Whh_lo, 8 = x-plane
// ([Wih_hi(8)|Wih_lo(8)|0(16)]). col = ntile*16 + (l&15) = gate row 0..511.
__global__ void pack_wB_k(const float* __restrict__ W_hh, const float* __restrict__ W_ih,
                          ushort* __restrict__ wpB)
{
    int i = blockIdx.x * 256 + threadIdx.x;     // 0 .. 147455
    if (i >= 147456) return;
    int frag = i >> 9, lj = i & 511;
    int kt = frag >> 5, ntile = frag & 31;
    int l = lj >> 3, j = lj & 7;
    int klocal = (l >> 4) * 8 + j;              // 0..31
    int col = ntile * 16 + (l & 15);            // gate row 0..511
    float v; int hsel;
    if (kt < 8) {
        int k = (kt & 3) * 32 + klocal;
        hsel = kt >> 2;
        v = W_hh[col * 128 + k];
    } else {
        if (klocal < 8)       { v = W_ih[col * 8 + klocal];       hsel = 0; }
        else if (klocal < 16) { v = W_ih[col * 8 + (klocal - 8)]; hsel = 1; }
        else                  { v = 0.0f;                          hsel = 0; }
    }
    ushort h, lo; bsplit(v, h, lo);
    wpB[i] = hsel ? lo : h;
}

// ---------------- LSTM scan: stacked split-bf16 MFMA ----------------
// 64 wgs x 512 thr (8 waves). wg owns 16 sequences (one M-tile) for 64 steps.
// Wave w computes gate cols g*128 + w*16 + (l&15) for g=0..3 -> all 4 gates of
// the same 16 hidden cols -> gate math fully in-lane (C/D: col=l&15,
// row=(l>>4)*4+reg). h passes step-to-step via double-buffered LDS planes
// (stride-40 rows -> 2-way banks on ds_read_b128). Raw s_barrier + lgkmcnt(0)
// only: the hs_f global scatter stores are NEVER drained in-loop (no vmcnt(0)).
__global__ __launch_bounds__(512, 2) void lstm_mfma_k(
    const ushort* __restrict__ cur_hi, const ushort* __restrict__ cur_lo,
    const ushort* __restrict__ wpB, const float* __restrict__ b_ih,
    const float* __restrict__ b_hh, ushort* __restrict__ hs_f)
{
    __shared__ __align__(16) ushort zone[2][8][640];   // [buf][plane][16 rows x 40]

    const int t  = threadIdx.x;
    const int w  = t >> 6, l = t & 63;
    const int li = l & 15, lk = l >> 4;
    const int qblk = blockIdx.x;
    const int q0   = qblk * 16;

    // B-frags: 4 gates x 9 kt planes = 144 VGPRs
    short8 bw[4][9];
#pragma unroll
    for (int g = 0; g < 4; ++g)
#pragma unroll
        for (int kt = 0; kt < 9; ++kt)
            bw[g][kt] = *(const short8*)(wpB + (size_t)(kt * 32 + g * 8 + w) * 512 + l * 8);

    float bsum[4];
#pragma unroll
    for (int g = 0; g < 4; ++g) {
        int gc = g * 128 + w * 16 + li;
        bsum[g] = b_ih[gc] + b_hh[gc];
    }

    for (int i = t; i < 2560; i += 512) ((uint*)&zone[0][0][0])[i] = 0;  // h0 = 0
    float cc[4] = {0.0f, 0.0f, 0.0f, 0.0f};
    __syncthreads();

    const int zp_hi = w >> 1, zp_lo = 4 + (w >> 1);
    const int jl    = (w & 1) * 16 + li;
    const int roff  = li * 40 + lk * 8;

    auto dostep = [&](int step, int p) {
        const int pn = p ^ 1;
        // x A-frag: lk=0 -> x_hi row, lk=1 -> x_lo row, lk>=2 -> zero-B cols
        short8 xa = (short8){0, 0, 0, 0, 0, 0, 0, 0};
        const size_t xb = ((size_t)step * 1024 + q0 + li) * 8;
        if (lk == 0)      xa = *(const short8*)(cur_hi + xb);
        else if (lk == 1) xa = *(const short8*)(cur_lo + xb);

        short8 ah[8];
#pragma unroll
        for (int kt = 0; kt < 8; ++kt)
            ah[kt] = *(const short8*)&zone[p][kt][roff];

        f32x4 acc[4];
#pragma unroll
        for (int g = 0; g < 4; ++g)
            acc[g] = (f32x4){bsum[g], bsum[g], bsum[g], bsum[g]};
#pragma unroll
        for (int kt = 0; kt < 8; ++kt)
#pragma unroll
            for (int g = 0; g < 4; ++g)
                acc[g] = MFMA16(ah[kt], bw[g][kt], acc[g]);
#pragma unroll
        for (int g = 0; g < 4; ++g)
            acc[g] = MFMA16(xa, bw[g][8], acc[g]);

        // gates (torch order i,f,g,o) fully in-register
        const size_t hb = (size_t)(step * 64 + qblk) * 8 * 512;
#pragma unroll
        for (int r2 = 0; r2 < 4; ++r2) {
            float pi = acc[0][r2], pf = acc[1][r2], pg = acc[2][r2], po = acc[3][r2];
            cc[r2] = sigf(pf) * cc[r2] + sigf(pi) * tanh_f(pg);
            float hv = sigf(po) * tanh_f(cc[r2]);
            ushort hh, hl; bsplit(hv, hh, hl);
            int srow = lk * 4 + r2;
            zone[pn][zp_hi][srow * 40 + jl] = hh;
            zone[pn][zp_lo][srow * 40 + jl] = hl;
            hs_f[hb + zp_hi * 512 + srow * 32 + jl] = hh;   // fire-and-forget
            hs_f[hb + zp_lo * 512 + srow * 32 + jl] = hl;
        }
        // drain LDS only; global stores stay in flight (no vmcnt(0) in loop)
        asm volatile("s_waitcnt lgkmcnt(0)\n\ts_barrier" ::: "memory");
    };

    for (int s2 = 0; s2 < 32; ++s2) { dostep(s2 * 2, 0); dostep(s2 * 2 + 1, 1); }
}

// ---------------- MLP + head for one roll: stacked split-bf16 MFMA ----------
// 1024 wgs (b x 16 q-groups) x 256 thr (4 waves). wg owns 64 items (M=64).
__global__ __launch_bounds__(256, 2) void mlp_mfma_k(
    const ushort* __restrict__ hs_f,
    const ushort* __restrict__ hi_hi, const ushort* __restrict__ hi_lo,
    const float* __restrict__ r, int jstep,
    const ushort* __restrict__ wp1, const ushort* __restrict__ wp2,
    const ushort* __restrict__ wp3,
    const float* __restrict__ W1, const float* __restrict__ b1,
    const float* __restrict__ b2, const float* __restrict__ b3,
    const float* __restrict__ Wf, const float* __restrict__ bfp,
    ushort* __restrict__ cur_hi, ushort* __restrict__ cur_lo,
    float* __restrict__ out)
{
    __shared__ __align__(16) ushort h1f[8 * 4 * 640];   // [plane8][mt4][16x40]  40KB
    __shared__ __align__(16) ushort h2f[4 * 4 * 640];   // [plane4][mt4][16x40]  20KB

    const int t = threadIdx.x;
    const int w = t >> 6, l = t & 63;
    const int lrow = l & 15, lk = l >> 4;
    const int b = blockIdx.x >> 4;
    const int qb = (blockIdx.x & 15) * 64;
    const float rb = r[b * 4 + jstep];

    // ============ GEMM1: h1 = relu([hs|hi|r] @ W1^T + b1), K'=512 ============
    f32x4 acc[4][2];
#pragma unroll
    for (int nt = 0; nt < 2; ++nt) {
        int col = w * 32 + nt * 16 + lrow;
        float bias = b1[col] + rb * W1[col * 257 + 256];   // fold r-col + b1 (fp32)
#pragma unroll
        for (int mt = 0; mt < 4; ++mt)
            acc[mt][nt] = (f32x4){bias, bias, bias, bias};
    }

#pragma unroll 4
    for (int kt = 0; kt < 16; ++kt) {
        short8 av[4];
#pragma unroll
        for (int mt = 0; mt < 4; ++mt) {
            if (kt < 8) {        // hs planes straight from lstm frag dump
                int qm = (qb >> 4) + mt;
                av[mt] = *(const short8*)(hs_f + ((size_t)(b * 64 + qm) * 8 + kt) * 512
                                          + lrow * 32 + lk * 8);
            } else {             // hidden_intensity, row-major is frag-friendly
                int q = qb + mt * 16 + lrow;
                int ktl = kt - 8;
                const ushort* src = (ktl < 4) ? hi_hi : hi_lo;
                av[mt] = *(const short8*)(src + (size_t)(b * 256 + (q >> 2)) * 128
                                          + (ktl & 3) * 32 + lk * 8);
            }
        }
#pragma unroll
        for (int nt = 0; nt < 2; ++nt) {
            short8 bv = *(const short8*)(wp1 + (size_t)(kt * 8 + w * 2 + nt) * 512 + l * 8);
#pragma unroll
            for (int mt = 0; mt < 4; ++mt)
                acc[mt][nt] = MFMA16(av[mt], bv, acc[mt][nt]);
        }
    }

    // epilogue1: relu + split -> h1 planes (hi: plane w, lo: plane 4+w)
#pragma unroll
    for (int mt = 0; mt < 4; ++mt)
#pragma unroll
        for (int nt = 0; nt < 2; ++nt)
#pragma unroll
            for (int reg = 0; reg < 4; ++reg) {
                float v = fmaxf(acc[mt][nt][reg], 0.0f);
                ushort vh, vl; bsplit(v, vh, vl);
                int s = lk * 4 + reg, jj = nt * 16 + lrow;
                h1f[(w * 4 + mt) * 640 + s * 40 + jj]       = vh;
                h1f[((4 + w) * 4 + mt) * 640 + s * 40 + jj] = vl;
            }
    __syncthreads();

    // ============ GEMM2: h2 = relu(h1 @ W2^T + b2), K'=256, cols 16w.. =======
    f32x4 acc2[4];
    {
        float bias = b2[16 * w + lrow];
#pragma unroll
        for (int mt = 0; mt < 4; ++mt)
            acc2[mt] = (f32x4){bias, bias, bias, bias};
    }
#pragma unroll
    for (int kt = 0; kt < 8; ++kt) {
        short8 bv = *(const short8*)(wp2 + (size_t)(kt * 4 + w) * 512 + l * 8);
#pragma unroll
        for (int mt = 0; mt < 4; ++mt) {
            short8 a = *(const short8*)&h1f[(kt * 4 + mt) * 640 + lrow * 40 + lk * 8];
            acc2[mt] = MFMA16(a, bv, acc2[mt]);
        }
    }
    // epilogue2: relu + split -> h2 planes (hi: col>>5, lo: 2+(col>>5))
#pragma unroll
    for (int mt = 0; mt < 4; ++mt)
#pragma unroll
        for (int reg = 0; reg < 4; ++reg) {
            float v = fmaxf(acc2[mt][reg], 0.0f);
            ushort vh, vl; bsplit(v, vh, vl);
            int s = lk * 4 + reg, jl2 = (w & 1) * 16 + lrow;
            h2f[((w >> 1) * 4 + mt) * 640 + s * 40 + jl2]       = vh;
            h2f[((2 + (w >> 1)) * 4 + mt) * 640 + s * 40 + jl2] = vl;
        }
    __syncthreads();

    // ============ GEMM3: pr = h2 @ W3^T + b3, K'=128; wave w -> rows 16w.. ===
    f32x4 acc3 = (f32x4){0.0f, 0.0f, 0.0f, 0.0f};
#pragma unroll
    for (int kt = 0; kt < 4; ++kt) {
        short8 a  = *(const short8*)&h2f[(kt * 4 + w) * 640 + lrow * 40 + lk * 8];
        short8 bv = *(const short8*)(wp3 + (size_t)kt * 512 + l * 8);
        acc3 = MFMA16(a, bv, acc3);
    }

    // epilogue3: cur(hi/lo) <- pr (raw, split); head: sum relu(pr)*Wf over C, Ct
    const int c = lrow;
    const float b3v = (c < 8) ? b3[c] : 0.0f;
    const float wfv = (c < 8) ? Wf[c] : 0.0f;
    float fr[4];
#pragma unroll
    for (int reg = 0; reg < 4; ++reg) {
        float pr = acc3[reg] + b3v;
        if (c < 8) {
            int row = 16 * w + lk * 4 + reg;
            size_t idx = ((size_t)(b * 1024 + qb + row)) * 8 + c;
            ushort ph, plo; bsplit(pr, ph, plo);
            cur_hi[idx] = ph; cur_lo[idx] = plo;
        }
        fr[reg] = (c < 8) ? fmaxf(pr, 0.0f) * wfv : 0.0f;
    }
#pragma unroll
    for (int reg = 0; reg < 4; ++reg) {
        fr[reg] += __shfl_xor(fr[reg], 1);
        fr[reg] += __shfl_xor(fr[reg], 2);
        fr[reg] += __shfl_xor(fr[reg], 4);
    }
    if ((l & 15) == 0) {
        int n = (qb + 16 * w + lk * 4) >> 2;
        float v = fr[0] + fr[1] + fr[2] + fr[3] + 4.0f * bfp[0];
        out[(size_t)(b * 256 + n) * 4 + jstep] = v;
    }
}

extern "C" void kernel_launch(void* const* d_in, const int* in_sizes, int n_in,
                              void* d_out, int out_size, void* d_ws, size_t ws_size,
                              hipStream_t stream)
{
    const float* x   = (const float*)d_in[0];
    const float* hi  = (const float*)d_in[1];
    const float* r   = (const float*)d_in[2];
    const float* Wih = (const float*)d_in[3];
    const float* Whh = (const float*)d_in[4];
    const float* bih = (const float*)d_in[5];
    const float* bhh = (const float*)d_in[6];
    const float* W1  = (const float*)d_in[7];
    const float* b1  = (const float*)d_in[8];
    const float* W2  = (const float*)d_in[9];
    const float* b2  = (const float*)d_in[10];
    const float* W3  = (const float*)d_in[11];
    const float* b3  = (const float*)d_in[12];
    const float* Wf  = (const float*)d_in[13];
    const float* bf  = (const float*)d_in[14];
    float* out = (float*)d_out;

    ushort* cur_hi = (ushort*)d_ws;                    // 524288
    ushort* cur_lo = cur_hi + 524288;                  // 524288
    ushort* hs_f   = cur_lo + 524288;                  // 16777216 (32 MB)
    ushort* hi_hi  = hs_f + 16777216;                  // 2097152
    ushort* hi_lo  = hi_hi + 2097152;                  // 2097152
    ushort* wp1    = hi_lo + 2097152;                  // 65536
    ushort* wp2    = wp1 + 65536;                      // 16384
    ushort* wp3    = wp2 + 16384;                      // 2048
    ushort* wpB    = wp3 + 2048;                       // 147456

    init_cur_k<<<2048, 256, 0, stream>>>(x, cur_hi, cur_lo);
    split_hi_k<<<8192, 256, 0, stream>>>(hi, hi_hi, hi_lo);
    pack_w_k<<<328, 256, 0, stream>>>(W1, W2, W3, wp1, wp2, wp3);
    pack_wB_k<<<576, 256, 0, stream>>>(Whh, Wih, wpB);
    for (int j = 0; j < 4; ++j) {
        lstm_mfma_k<<<64, 512, 0, stream>>>(cur_hi, cur_lo, wpB, bih, bhh, hs_f);
        mlp_mfma_k<<<1024, 256, 0, stream>>>(hs_f, hi_hi, hi_lo, r, j,
                                             wp1, wp2, wp3, W1, b1, b2, b3,
                                             Wf, bf, cur_hi, cur_lo, out);
    }
}

// Round 6
// 415.219 us; speedup vs baseline: 6.0410x; 1.6045x over previous
//
#include <hip/hip_runtime.h>
#include <hip/hip_bf16.h>

// B=64 (LSTM time axis via torch batch_first quirk), L=64 (only col 63 used),
// N=256, C=8, Ct=4 -> NQ=1024 sequences, H=128, 4H=512, RH1=128, RH2=64, S=4.
//
// All matmuls use STACKED split-bf16 MFMA: f = hi + lo (two bf16); stack
// [A_hi|A_lo] along K against [B_hi;B_lo] in fp32 accum. LSTM blocks own 4
// sequences placed at M-rows {0,4,8,12} so that C-reg 0 of lane (lk,li) is
// exactly item (seq=lk, col=cg*16+li): gate math is 1 item/lane, fully packed.

typedef __attribute__((ext_vector_type(8))) short short8;   // 8 bf16 in 4 VGPRs
typedef __attribute__((ext_vector_type(4))) float f32x4;

#define MFMA16(a, b, c) __builtin_amdgcn_mfma_f32_16x16x32_bf16(a, b, c, 0, 0, 0)

__device__ __forceinline__ float sigf(float x)   { return 1.0f / (1.0f + __expf(-x)); }
__device__ __forceinline__ float tanh_f(float x) { return 1.0f - 2.0f / (__expf(2.0f * x) + 1.0f); }

__device__ __forceinline__ ushort bf16_rne(float v) {
    unsigned u = __float_as_uint(v);
    return (ushort)((u + 0x7FFFu + ((u >> 16) & 1u)) >> 16);
}
__device__ __forceinline__ void bsplit(float v, ushort& h, ushort& l) {
    h = bf16_rne(v);
    float fh = __uint_as_float(((unsigned)h) << 16);
    l = bf16_rne(v - fh);
}

// ---------------- init: cur(hi/lo) <- x[:, 63, :, :] ----------------
__global__ void init_cur_k(const float* __restrict__ x,
                           ushort* __restrict__ cur_hi, ushort* __restrict__ cur_lo)
{
    int i   = blockIdx.x * 256 + threadIdx.x;   // 0 .. 524287
    int b   = i >> 13;
    int rem = i & 8191;
    ushort h, l; bsplit(x[(size_t)b * 524288 + 63 * 8192 + rem], h, l);
    cur_hi[i] = h; cur_lo[i] = l;
}

// ---------------- split hidden_intensity to bf16 hi/lo, once ----------------
__global__ void split_hi_k(const float* __restrict__ hi,
                           ushort* __restrict__ hi_hi, ushort* __restrict__ hi_lo)
{
    int i = blockIdx.x * 256 + threadIdx.x;     // 0 .. 2097151
    ushort h, l; bsplit(hi[i], h, l);
    hi_hi[i] = h; hi_lo[i] = l;
}

// ---------------- pack W1/W2/W3 into stacked-K MFMA B-frags, once ------------
// B-frag (16x16x32): lane l holds B[k = (l>>4)*8 + j][col = l&15], j=0..7.
__global__ void pack_w_k(const float* __restrict__ W1, const float* __restrict__ W2,
                         const float* __restrict__ W3, ushort* __restrict__ wp1,
                         ushort* __restrict__ wp2, ushort* __restrict__ wp3)
{
    int i = blockIdx.x * 256 + threadIdx.x;
    if (i < 65536) {                       // wp1 [kt16][nt8][512]; K'=512 over [hs|hi]
        int fragid = i >> 9, lj = i & 511;
        int kt = fragid >> 3, nt = fragid & 7;
        int l = lj >> 3, j = lj & 7;
        int klocal = (l >> 4) * 8 + j;
        int k = (kt >> 3) * 128 + (kt & 3) * 32 + klocal;   // source k (0..255)
        int hsel = (kt >> 2) & 1;
        int o = nt * 16 + (l & 15);
        ushort h, lo; bsplit(W1[o * 257 + k], h, lo);
        wp1[i] = hsel ? lo : h;
    } else if (i < 65536 + 16384) {        // wp2 [kt8][nt4][512]; K'=256
        int ii = i - 65536;
        int fragid = ii >> 9, lj = ii & 511;
        int kt = fragid >> 2, nt = fragid & 3;
        int l = lj >> 3, j = lj & 7;
        int klocal = (l >> 4) * 8 + j;
        int k = (kt & 3) * 32 + klocal;                     // 0..127
        int hsel = (kt >> 2) & 1;
        int o = nt * 16 + (l & 15);
        ushort h, lo; bsplit(W2[o * 128 + k], h, lo);
        wp2[ii] = hsel ? lo : h;
    } else if (i < 65536 + 16384 + 2048) { // wp3 [kt4][512]; K'=128
        int ii = i - 65536 - 16384;
        int kt = ii >> 9, lj = ii & 511;
        int l = lj >> 3, j = lj & 7;
        int klocal = (l >> 4) * 8 + j;
        int k = (kt & 1) * 32 + klocal;                     // 0..63
        int hsel = kt >> 1;
        int c = l & 15;
        float v = (c < 8) ? W3[c * 64 + k] : 0.0f;
        ushort h, lo; bsplit(v, h, lo);
        wp3[ii] = hsel ? lo : h;
    }
}

// ---------------- pack [W_hh(stacked) | W_ih(stacked)] B-frags, once ---------
// wpB [kt(9)][ntile(32)][512]: kt 0..3 = Whh_hi, 4..7 = Whh_lo, 8 = x-plane
// ([Wih_hi(8)|Wih_lo(8)|0(16)]). col = ntile*16 + (l&15) = gate row 0..511.
__global__ void pack_wB_k(const float* __restrict__ W_hh, const float* __restrict__ W_ih,
                          ushort* __restrict__ wpB)
{
    int i = blockIdx.x * 256 + threadIdx.x;     // 0 .. 147455
    if (i >= 147456) return;
    int frag = i >> 9, lj = i & 511;
    int kt = frag >> 5, ntile = frag & 31;
    int l = lj >> 3, j = lj & 7;
    int klocal = (l >> 4) * 8 + j;              // 0..31
    int col = ntile * 16 + (l & 15);            // gate row 0..511
    float v; int hsel;
    if (kt < 8) {
        int k = (kt & 3) * 32 + klocal;
        hsel = kt >> 2;
        v = W_hh[col * 128 + k];
    } else {
        if (klocal < 8)       { v = W_ih[col * 8 + klocal];       hsel = 0; }
        else if (klocal < 16) { v = W_ih[col * 8 + (klocal - 8)]; hsel = 1; }
        else                  { v = 0.0f;                          hsel = 0; }
    }
    ushort h, lo; bsplit(v, h, lo);
    wpB[i] = hsel ? lo : h;
}

// ---------------- LSTM scan: stacked split-bf16 MFMA, 256 blocks ------------
// 256 wgs x 512 thr (8 waves = col-groups). wg owns 4 sequences at M-rows
// {0,4,8,12} (rows else are zero pad). Wave cg computes gate cols
// g*128 + cg*16 + (l&15), g=0..3. C-reg 0 of lane (lk,li) = preact of item
// (seq=lk, col=cg*16+li) -> gate math 1 item/lane, cc = 1 register.
// h passes step-to-step via double-buffered LDS planes (stride-40 rows);
// x for step+1 prefetched at step top (hides HBM latency); hs stores are
// fire-and-forget; in-loop barrier drains lgkmcnt only (no vmcnt(0)).
__global__ __launch_bounds__(512, 2) void lstm_mfma_k(
    const ushort* __restrict__ cur_hi, const ushort* __restrict__ cur_lo,
    const ushort* __restrict__ wpB, const float* __restrict__ b_ih,
    const float* __restrict__ b_hh, ushort* __restrict__ hs_hi,
    ushort* __restrict__ hs_lo)
{
    __shared__ __align__(16) ushort zone[2][8][640];   // 20 KB

    const int t  = threadIdx.x;
    const int cg = t >> 6, l = t & 63;
    const int li = l & 15, lk = l >> 4;
    const int q0 = blockIdx.x * 4;

    // B-frags: 4 gates x 9 kt planes (8 h + 1 x) = 144 regs
    short8 bw[4][9];
#pragma unroll
    for (int g = 0; g < 4; ++g)
#pragma unroll
        for (int kt = 0; kt < 9; ++kt)
            bw[g][kt] = *(const short8*)(wpB + (size_t)(kt * 32 + g * 8 + cg) * 512 + l * 8);

    float bsum[4];
#pragma unroll
    for (int g = 0; g < 4; ++g) {
        int gc = g * 128 + cg * 16 + li;
        bsum[g] = b_ih[gc] + b_hh[gc];
    }

    for (int i = t; i < 5120; i += 512) ((uint*)zone)[i] = 0;   // both bufs = 0
    float cc = 0.0f;
    __syncthreads();

    const int zp_hi = cg >> 1, zp_lo = 4 + (cg >> 1);
    const int jl    = (cg & 1) * 16 + li;
    const int roff  = li * 40 + lk * 8;       // A-frag read offset in a plane
    const int srow  = lk * 4;                 // this lane's item row (seq lk)

    // branchless per-lane x source: lk=0 -> x_hi, lk=1 -> x_lo, lk>=2 -> any
    // finite garbage (pairs with ZERO rows of the x B-plane -> contributes 0).
    const ushort* xsrc = (lk == 0) ? cur_hi : ((lk == 1) ? cur_lo : cur_hi);
    const size_t  xoff = (size_t)(q0 + (li >> 2)) * 8;

    ushort* ph = hs_hi + (size_t)(q0 + lk) * 128 + cg * 16 + li;
    ushort* pl = hs_lo + (size_t)(q0 + lk) * 128 + cg * 16 + li;

    short8 xaA = *(const short8*)(xsrc + xoff);   // x(step 0)
    short8 xaB;

    auto dostep = [&](int step, int p, short8 xa, short8& xnext) {
        const int pn = p ^ 1;
        // prefetch next step's x (step 63 wraps to 0: harmless, unused)
        xnext = *(const short8*)(xsrc + (size_t)(((step + 1) & 63)) * 8192 + xoff);

        short8 ah[8];
#pragma unroll
        for (int kt = 0; kt < 8; ++kt)
            ah[kt] = *(const short8*)&zone[p][kt][roff];

        f32x4 acc[4];
#pragma unroll
        for (int g = 0; g < 4; ++g)
            acc[g] = (f32x4){bsum[g], bsum[g], bsum[g], bsum[g]};
#pragma unroll
        for (int kt = 0; kt < 8; ++kt)
#pragma unroll
            for (int g = 0; g < 4; ++g)
                acc[g] = MFMA16(ah[kt], bw[g][kt], acc[g]);
#pragma unroll
        for (int g = 0; g < 4; ++g)
            acc[g] = MFMA16(xa, bw[g][8], acc[g]);

        // gate math (torch order i,f,g,o): ONE packed item per lane (reg 0)
        float pi = acc[0][0], pf = acc[1][0], pg = acc[2][0], po = acc[3][0];
        cc = sigf(pf) * cc + sigf(pi) * tanh_f(pg);
        float hv = sigf(po) * tanh_f(cc);
        ushort hh, hl; bsplit(hv, hh, hl);
        zone[pn][zp_hi][srow * 40 + jl] = hh;
        zone[pn][zp_lo][srow * 40 + jl] = hl;
        ph[(size_t)step * 131072] = hh;           // fire-and-forget
        pl[(size_t)step * 131072] = hl;
        // drain LDS only; global loads/stores stay in flight
        asm volatile("s_waitcnt lgkmcnt(0)\n\ts_barrier" ::: "memory");
    };

    for (int s2 = 0; s2 < 32; ++s2) {
        dostep(s2 * 2,     0, xaA, xaB);
        dostep(s2 * 2 + 1, 1, xaB, xaA);
    }
}

// ---------------- MLP + head for one roll: stacked split-bf16 MFMA ----------
// 1024 wgs (b x 16 q-groups) x 256 thr (4 waves). wg owns 64 items (M=64).
__global__ __launch_bounds__(256, 2) void mlp_mfma_k(
    const ushort* __restrict__ hs_hi, const ushort* __restrict__ hs_lo,
    const ushort* __restrict__ hi_hi, const ushort* __restrict__ hi_lo,
    const float* __restrict__ r, int jstep,
    const ushort* __restrict__ wp1, const ushort* __restrict__ wp2,
    const ushort* __restrict__ wp3,
    const float* __restrict__ W1, const float* __restrict__ b1,
    const float* __restrict__ b2, const float* __restrict__ b3,
    const float* __restrict__ Wf, const float* __restrict__ bfp,
    ushort* __restrict__ cur_hi, ushort* __restrict__ cur_lo,
    float* __restrict__ out)
{
    __shared__ __align__(16) ushort h1f[8 * 4 * 640];   // [plane8][mt4][16x40]  40KB
    __shared__ __align__(16) ushort h2f[4 * 4 * 640];   // [plane4][mt4][16x40]  20KB

    const int t = threadIdx.x;
    const int w = t >> 6, l = t & 63;
    const int lrow = l & 15, lk = l >> 4;
    const int b = blockIdx.x >> 4;
    const int qb = (blockIdx.x & 15) * 64;
    const float rb = r[b * 4 + jstep];

    // ============ GEMM1: h1 = relu([hs|hi|r] @ W1^T + b1), K'=512 ============
    f32x4 acc[4][2];
#pragma unroll
    for (int nt = 0; nt < 2; ++nt) {
        int col = w * 32 + nt * 16 + lrow;
        float bias = b1[col] + rb * W1[col * 257 + 256];   // fold r-col + b1 (fp32)
#pragma unroll
        for (int mt = 0; mt < 4; ++mt)
            acc[mt][nt] = (f32x4){bias, bias, bias, bias};
    }

#pragma unroll 4
    for (int kt = 0; kt < 16; ++kt) {
        short8 av[4];
#pragma unroll
        for (int mt = 0; mt < 4; ++mt) {
            int q = qb + mt * 16 + lrow;
            if (kt < 8) {        // hs, row-major split arrays
                const ushort* src = (kt < 4) ? hs_hi : hs_lo;
                av[mt] = *(const short8*)(src + (size_t)(b * 1024 + q) * 128
                                          + (kt & 3) * 32 + lk * 8);
            } else {             // hidden_intensity
                int ktl = kt - 8;
                const ushort* src = (ktl < 4) ? hi_hi : hi_lo;
                av[mt] = *(const short8*)(src + (size_t)(b * 256 + (q >> 2)) * 128
                                          + (ktl & 3) * 32 + lk * 8);
            }
        }
#pragma unroll
        for (int nt = 0; nt < 2; ++nt) {
            short8 bv = *(const short8*)(wp1 + (size_t)(kt * 8 + w * 2 + nt) * 512 + l * 8);
#pragma unroll
            for (int mt = 0; mt < 4; ++mt)
                acc[mt][nt] = MFMA16(av[mt], bv, acc[mt][nt]);
        }
    }

    // epilogue1: relu + split -> h1 planes (hi: plane w, lo: plane 4+w)
#pragma unroll
    for (int mt = 0; mt < 4; ++mt)
#pragma unroll
        for (int nt = 0; nt < 2; ++nt)
#pragma unroll
            for (int reg = 0; reg < 4; ++reg) {
                float v = fmaxf(acc[mt][nt][reg], 0.0f);
                ushort vh, vl; bsplit(v, vh, vl);
                int s = lk * 4 + reg, jj = nt * 16 + lrow;
                h1f[(w * 4 + mt) * 640 + s * 40 + jj]       = vh;
                h1f[((4 + w) * 4 + mt) * 640 + s * 40 + jj] = vl;
            }
    __syncthreads();

    // ============ GEMM2: h2 = relu(h1 @ W2^T + b2), K'=256, cols 16w.. =======
    f32x4 acc2[4];
    {
        float bias = b2[16 * w + lrow];
#pragma unroll
        for (int mt = 0; mt < 4; ++mt)
            acc2[mt] = (f32x4){bias, bias, bias, bias};
    }
#pragma unroll
    for (int kt = 0; kt < 8; ++kt) {
        short8 bv = *(const short8*)(wp2 + (size_t)(kt * 4 + w) * 512 + l * 8);
#pragma unroll
        for (int mt = 0; mt < 4; ++mt) {
            short8 a = *(const short8*)&h1f[(kt * 4 + mt) * 640 + lrow * 40 + lk * 8];
            acc2[mt] = MFMA16(a, bv, acc2[mt]);
        }
    }
    // epilogue2: relu + split -> h2 planes (hi: col>>5, lo: 2+(col>>5))
#pragma unroll
    for (int mt = 0; mt < 4; ++mt)
#pragma unroll
        for (int reg = 0; reg < 4; ++reg) {
            float v = fmaxf(acc2[mt][reg], 0.0f);
            ushort vh, vl; bsplit(v, vh, vl);
            int s = lk * 4 + reg, jl2 = (w & 1) * 16 + lrow;
            h2f[((w >> 1) * 4 + mt) * 640 + s * 40 + jl2]       = vh;
            h2f[((2 + (w >> 1)) * 4 + mt) * 640 + s * 40 + jl2] = vl;
        }
    __syncthreads();

    // ============ GEMM3: pr = h2 @ W3^T + b3, K'=128; wave w -> rows 16w.. ===
    f32x4 acc3 = (f32x4){0.0f, 0.0f, 0.0f, 0.0f};
#pragma unroll
    for (int kt = 0; kt < 4; ++kt) {
        short8 a  = *(const short8*)&h2f[(kt * 4 + w) * 640 + lrow * 40 + lk * 8];
        short8 bv = *(const short8*)(wp3 + (size_t)kt * 512 + l * 8);
        acc3 = MFMA16(a, bv, acc3);
    }

    // epilogue3: cur(hi/lo) <- pr (raw, split); head: sum relu(pr)*Wf over C, Ct
    const int c = lrow;
    const float b3v = (c < 8) ? b3[c] : 0.0f;
    const float wfv = (c < 8) ? Wf[c] : 0.0f;
    float fr[4];
#pragma unroll
    for (int reg = 0; reg < 4; ++reg) {
        float pr = acc3[reg] + b3v;
        if (c < 8) {
            int row = 16 * w + lk * 4 + reg;
            size_t idx = ((size_t)(b * 1024 + qb + row)) * 8 + c;
            ushort p2h, p2l; bsplit(pr, p2h, p2l);
            cur_hi[idx] = p2h; cur_lo[idx] = p2l;
        }
        fr[reg] = (c < 8) ? fmaxf(pr, 0.0f) * wfv : 0.0f;
    }
#pragma unroll
    for (int reg = 0; reg < 4; ++reg) {
        fr[reg] += __shfl_xor(fr[reg], 1);
        fr[reg] += __shfl_xor(fr[reg], 2);
        fr[reg] += __shfl_xor(fr[reg], 4);
    }
    if ((l & 15) == 0) {
        int n = (qb + 16 * w + lk * 4) >> 2;
        float v = fr[0] + fr[1] + fr[2] + fr[3] + 4.0f * bfp[0];
        out[(size_t)(b * 256 + n) * 4 + jstep] = v;
    }
}

extern "C" void kernel_launch(void* const* d_in, const int* in_sizes, int n_in,
                              void* d_out, int out_size, void* d_ws, size_t ws_size,
                              hipStream_t stream)
{
    const float* x   = (const float*)d_in[0];
    const float* hi  = (const float*)d_in[1];
    const float* r   = (const float*)d_in[2];
    const float* Wih = (const float*)d_in[3];
    const float* Whh = (const float*)d_in[4];
    const float* bih = (const float*)d_in[5];
    const float* bhh = (const float*)d_in[6];
    const float* W1  = (const float*)d_in[7];
    const float* b1  = (const float*)d_in[8];
    const float* W2  = (const float*)d_in[9];
    const float* b2  = (const float*)d_in[10];
    const float* W3  = (const float*)d_in[11];
    const float* b3  = (const float*)d_in[12];
    const float* Wf  = (const float*)d_in[13];
    const float* bf  = (const float*)d_in[14];
    float* out = (float*)d_out;

    ushort* cur_hi = (ushort*)d_ws;                    // 524288
    ushort* cur_lo = cur_hi + 524288;                  // 524288
    ushort* hs_hi  = cur_lo + 524288;                  // 8388608
    ushort* hs_lo  = hs_hi + 8388608;                  // 8388608
    ushort* hi_hi  = hs_lo + 8388608;                  // 2097152
    ushort* hi_lo  = hi_hi + 2097152;                  // 2097152
    ushort* wp1    = hi_lo + 2097152;                  // 65536
    ushort* wp2    = wp1 + 65536;                      // 16384
    ushort* wp3    = wp2 + 16384;                      // 2048
    ushort* wpB    = wp3 + 2048;                       // 147456

    init_cur_k<<<2048, 256, 0, stream>>>(x, cur_hi, cur_lo);
    split_hi_k<<<8192, 256, 0, stream>>>(hi, hi_hi, hi_lo);
    pack_w_k<<<328, 256, 0, stream>>>(W1, W2, W3, wp1, wp2, wp3);
    pack_wB_k<<<576, 256, 0, stream>>>(Whh, Wih, wpB);
    for (int j = 0; j < 4; ++j) {
        lstm_mfma_k<<<256, 512, 0, stream>>>(cur_hi, cur_lo, wpB, bih, bhh,
                                             hs_hi, hs_lo);
        mlp_mfma_k<<<1024, 256, 0, stream>>>(hs_hi, hs_lo, hi_hi, hi_lo, r, j,
                                             wp1, wp2, wp3, W1, b1, b2, b3,
                                             Wf, bf, cur_hi, cur_lo, out);
    }
}